// Round 9
// baseline (21385.753 us; speedup 1.0000x reference)
//
#include <hip/hip_runtime.h>
#include <stdint.h>

// RankingLossL1: negative mining (L1 top-K) + margin ranking loss.
// N=50000 rows, D=128, T=1024 anchors/direction, K=10, GAMMA=1.
//
// Round-9. Post-mortem r7/r8: hipcc left per-thread arrays in scratch even at
// <=16 regs each (r8: VGPR=128 but 30 GB of HBM scratch traffic, VALUBusy
// 12%). Fix: the mine kernel has ZERO local arrays — all per-thread state is
// named scalars built by macros (SSA values; nothing for PromoteAlloca to
// miss):
//   * block = 64 anchors x one N-chunk (CH=3125). Anchors staged once into
//     padded LDS sA (stride 132). G streams in 64-row x 16-dim chunks through
//     a double-buffered padded LDS tile sG (stride 20; prefetch issued before
//     compute). Per thread: named a00..a33 over (4 anchors x 4 rows).
//   * Per 64-row tile: distances dumped to padded LDS sD (stride 65), then
//     each thread scans one anchor-quarter (16 rows) into a named top-10
//     cascade. Ties can't change the loss (only distance VALUES enter).
//   * Two-stage in-place merge (64 lists -> 8 -> 1), then wave-per-t loss.

#define NROWS 50000
#define DDIM  128
#define TT    1024
#define KK    10
#define NCH   16
#define CH    3125
#define TT2   (2 * TT)
#define BN    64
#define TK    16
#define NTIL  ((CH + BN - 1) / BN)  // 49
#define AW    132                    // sA stride (words)
#define GW    20                     // sG stride (words)
#define DW    65                     // sD stride (words)

typedef float f32x2 __attribute__((ext_vector_type(2)));
typedef float f32x4 __attribute__((ext_vector_type(4)));

#define BIGF 3.4e38f

// ---- named-scalar top-10 (ascending) ----
#define DECL_TOPK                                                       \
  float val0 = BIGF, val1 = BIGF, val2 = BIGF, val3 = BIGF, val4 = BIGF, \
        val5 = BIGF, val6 = BIGF, val7 = BIGF, val8 = BIGF, val9 = BIGF; \
  int idx0 = 0, idx1 = 0, idx2 = 0, idx3 = 0, idx4 = 0, idx5 = 0,        \
      idx6 = 0, idx7 = 0, idx8 = 0, idx9 = 0;

#define INS_STEP(V, I)                                \
  {                                                   \
    const bool lt_ = cv < (V);                        \
    const float tv_ = lt_ ? (V) : cv;                 \
    const int ti_ = lt_ ? (I) : ci;                   \
    (V) = lt_ ? cv : (V);                             \
    (I) = lt_ ? ci : (I);                             \
    cv = tv_;                                         \
    ci = ti_;                                         \
  }

#define INS_ALL                                                    \
  INS_STEP(val0, idx0) INS_STEP(val1, idx1) INS_STEP(val2, idx2)   \
  INS_STEP(val3, idx3) INS_STEP(val4, idx4) INS_STEP(val5, idx5)   \
  INS_STEP(val6, idx6) INS_STEP(val7, idx7) INS_STEP(val8, idx8)   \
  INS_STEP(val9, idx9)

// ---- distance accumulate: one f32x4 sub + 4 abs-adds ----
#define ACC(AF, GF, AC)                                              \
  {                                                                  \
    const f32x4 d_ = (AF) - (GF);                                    \
    AC += (fabsf(d_.x) + fabsf(d_.y)) + (fabsf(d_.z) + fabsf(d_.w)); \
  }

// 4-dim substep: 8 LDS b128 reads, 16 accumulates (all names local)
#define SUBSTEP(B, OFFA, OFFG)                                        \
  {                                                                   \
    const f32x4 af0 = *(const f32x4*)&sA[(ag + 0) * AW + (OFFA)];     \
    const f32x4 af1 = *(const f32x4*)&sA[(ag + 16) * AW + (OFFA)];    \
    const f32x4 af2 = *(const f32x4*)&sA[(ag + 32) * AW + (OFFA)];    \
    const f32x4 af3 = *(const f32x4*)&sA[(ag + 48) * AW + (OFFA)];    \
    const f32x4 gf0 = *(const f32x4*)&sG[B][(rg + 0) * GW + (OFFG)];  \
    const f32x4 gf1 = *(const f32x4*)&sG[B][(rg + 16) * GW + (OFFG)]; \
    const f32x4 gf2 = *(const f32x4*)&sG[B][(rg + 32) * GW + (OFFG)]; \
    const f32x4 gf3 = *(const f32x4*)&sG[B][(rg + 48) * GW + (OFFG)]; \
    ACC(af0, gf0, a00) ACC(af0, gf1, a01) ACC(af0, gf2, a02)          \
    ACC(af0, gf3, a03) ACC(af1, gf0, a10) ACC(af1, gf1, a11)          \
    ACC(af1, gf2, a12) ACC(af1, gf3, a13) ACC(af2, gf0, a20)          \
    ACC(af2, gf1, a21) ACC(af2, gf2, a22) ACC(af2, gf3, a23)          \
    ACC(af3, gf0, a30) ACC(af3, gf1, a31) ACC(af3, gf2, a32)          \
    ACC(af3, gf3, a33)                                                \
  }

#define CHUNK4(B, DC)                  \
  SUBSTEP(B, (DC) * TK + 0, 0)         \
  SUBSTEP(B, (DC) * TK + 4, 4)         \
  SUBSTEP(B, (DC) * TK + 8, 8)         \
  SUBSTEP(B, (DC) * TK + 12, 12)

// one dim-chunk: prefetch next chunk (named st_), compute, stash, barrier
#define STEP(DC)                                                           \
  {                                                                        \
    const bool more_ = ((DC) < 7) || (t + 1 < NTIL);                       \
    f32x4 st_ = {0.f, 0.f, 0.f, 0.f};                                      \
    if (more_) {                                                           \
      const int lrow_ = ((DC) < 7) ? (rts + srow) : (nrts + srow);         \
      const int ldim_ = ((DC) < 7) ? (((DC) + 1) * TK) : 0;                \
      st_ = *(const f32x4*)&G[(size_t)lrow_ * DDIM + ldim_ + 4 * sq];      \
    }                                                                      \
    CHUNK4((DC) & 1, DC)                                                   \
    if (more_) *(f32x4*)&sG[((DC)&1) ^ 1][srow * GW + 4 * sq] = st_;       \
    __syncthreads();                                                       \
  }

#define DUMP(I, J, AC) sD[(ag + 16 * (I)) * DW + 16 * (J) + rg] = AC;

// grid: 512 blocks x 256 threads; bid = (dir*16 + atile)*16 + chunk.
// bid%8 == chunk%8 -> each XCD sees only 2 chunks (3.2MB G set < 4MB L2).
__global__ __launch_bounds__(256, 2) void mine_kernel(
    const float* __restrict__ out1, const float* __restrict__ out2,
    const int* __restrict__ anc1, const int* __restrict__ anc2,
    float* __restrict__ cand_val, int* __restrict__ cand_idx) {
  const int tid = threadIdx.x;
  const int bid = blockIdx.x;
  const int chunk = bid & 15;
  const int combo = bid >> 4;
  const int dir = combo >> 4;
  const int atile = combo & 15;

  const float* __restrict__ A = dir ? out2 : out1;
  const float* __restrict__ G = dir ? out1 : out2;
  const int* __restrict__ anc = dir ? anc2 : anc1;

  const int ag = tid >> 4;  // anchor frag base: anchors {ag+16i}
  const int rg = tid & 15;  // row frag base:    rows    {16j+rg}

  __shared__ float sA[64 * AW];
  __shared__ float sG[2][BN * GW];
  __shared__ float sD[64 * DW];

  // stage 64 gathered anchor rows into padded sA (4 threads/row)
  {
    const int as = tid >> 2, qa = tid & 3;
    const int arow = anc[atile * 64 + as];
    const float* ap = A + (size_t)arow * DDIM + qa * 32;
    float* dp = &sA[as * AW + qa * 32];
#pragma unroll
    for (int c = 0; c < 8; c++)
      *(f32x4*)&dp[4 * c] = *(const f32x4*)&ap[4 * c];
  }

  const int r0 = chunk * CH;
  const int srow = tid >> 2;  // staging row 0..63
  const int sq = tid & 3;     // staging 16B quarter

  // prologue: chunk 0 of tile 0 -> buffer 0
  {
    const f32x4 st_ = *(const f32x4*)&G[(size_t)(r0 + srow) * DDIM + 4 * sq];
    *(f32x4*)&sG[0][srow * GW + 4 * sq] = st_;
  }
  __syncthreads();

  DECL_TOPK

#pragma unroll 1
  for (int t = 0; t < NTIL; t++) {
    const int ts = r0 + t * BN;
    const int rts = (t < NTIL - 1) ? ts : (r0 + CH - BN);  // clamped tail
    const int nrts = (t + 1 < NTIL - 1) ? (ts + BN) : (r0 + CH - BN);

    float a00 = 0.f, a01 = 0.f, a02 = 0.f, a03 = 0.f;
    float a10 = 0.f, a11 = 0.f, a12 = 0.f, a13 = 0.f;
    float a20 = 0.f, a21 = 0.f, a22 = 0.f, a23 = 0.f;
    float a30 = 0.f, a31 = 0.f, a32 = 0.f, a33 = 0.f;

    STEP(0) STEP(1) STEP(2) STEP(3) STEP(4) STEP(5) STEP(6) STEP(7)

    // dump 64x64 distance tile to padded LDS
    DUMP(0, 0, a00) DUMP(0, 1, a01) DUMP(0, 2, a02) DUMP(0, 3, a03)
    DUMP(1, 0, a10) DUMP(1, 1, a11) DUMP(1, 2, a12) DUMP(1, 3, a13)
    DUMP(2, 0, a20) DUMP(2, 1, a21) DUMP(2, 2, a22) DUMP(2, 3, a23)
    DUMP(3, 0, a30) DUMP(3, 1, a31) DUMP(3, 2, a32) DUMP(3, 3, a33)
    __syncthreads();

    // scan: thread -> anchor (tid&63), quarter (tid>>6): 16 rows
    {
      const int a = tid & 63;
      const int q = tid >> 6;
      const float* dp = &sD[a * DW + 16 * q];
#pragma unroll
      for (int rr = 0; rr < 16; rr++) {
        const float v = dp[rr];
        const int row = rts + 16 * q + rr;
        if (v < val9 && row >= ts) {
          float cv = v;
          int ci = row;
          INS_ALL
        }
      }
    }
    // sD not rewritten until after 8 barriers of the next tile -> safe
  }

  // write this (chunk, quarter) sub-list: row g = chunk*4 + q, layout
  // [g*KK + i][slot] -> coalesced writes and merge reads
  {
    const int a = tid & 63;
    const int q = tid >> 6;
    const int slot = dir * TT + atile * 64 + a;
    const size_t base = (size_t)((chunk * 4 + q) * KK) * TT2 + slot;
#define WOUT(i)                                   \
    cand_val[base + (size_t)(i) * TT2] = val##i;  \
    cand_idx[base + (size_t)(i) * TT2] = idx##i;
    WOUT(0) WOUT(1) WOUT(2) WOUT(3) WOUT(4)
    WOUT(5) WOUT(6) WOUT(7) WOUT(8) WOUT(9)
#undef WOUT
  }
}

// stage 1: 64 lists -> 8 per slot (16384 threads), in place
__global__ void merge1_kernel(float* __restrict__ cand_val,
                              int* __restrict__ cand_idx) {
  const int tid = blockIdx.x * blockDim.x + threadIdx.x;
  const int slot = tid & (TT2 - 1);
  const int part = tid >> 11;  // 0..7
  DECL_TOPK
  for (int c = 0; c < 8 * KK; c++) {
    const size_t o = (size_t)(part * 8 * KK + c) * TT2 + slot;
    const float v = cand_val[o];
    if (v < val9) {
      float cv = v;
      int ci = cand_idx[o];
      INS_ALL
    }
  }
  const size_t base = (size_t)(part * 8 * KK) * TT2 + slot;
#define WOUT(i)                                   \
  cand_val[base + (size_t)(i) * TT2] = val##i;    \
  cand_idx[base + (size_t)(i) * TT2] = idx##i;
  WOUT(0) WOUT(1) WOUT(2) WOUT(3) WOUT(4)
  WOUT(5) WOUT(6) WOUT(7) WOUT(8) WOUT(9)
#undef WOUT
}

// stage 2: 8 lists -> final negatives (2048 threads)
__global__ void merge2_kernel(const float* __restrict__ cand_val,
                              const int* __restrict__ cand_idx,
                              int* __restrict__ neg) {
  const int slot = blockIdx.x * blockDim.x + threadIdx.x;
  if (slot >= TT2) return;
  DECL_TOPK
  for (int p = 0; p < 8; p++)
    for (int i = 0; i < KK; i++) {
      const size_t o = (size_t)(p * 8 * KK + i) * TT2 + slot;
      const float v = cand_val[o];
      if (v < val9) {
        float cv = v;
        int ci = cand_idx[o];
        INS_ALL
      }
    }
  int* np = neg + (size_t)slot * KK;
  np[0] = idx0; np[1] = idx1; np[2] = idx2; np[3] = idx3; np[4] = idx4;
  np[5] = idx5; np[6] = idx6; np[7] = idx7; np[8] = idx8; np[9] = idx9;
}

__global__ void zero_kernel(float* __restrict__ out) {
  if (threadIdx.x == 0) out[0] = 0.f;
}

__global__ void loss_kernel(const float* __restrict__ out1,
                            const float* __restrict__ out2,
                            const int* __restrict__ anc1,
                            const int* __restrict__ anc2,
                            const int* __restrict__ neg,  // [2][TT][KK]
                            float* __restrict__ out) {
  const int lane = threadIdx.x & 63;
  const int w = threadIdx.x >> 6;
  const int t = blockIdx.x * 4 + w;  // one wave per t
  const int a1 = anc1[t];
  const int a2 = anc2[t];
  const int e = lane * 2;

  const f32x2 x1 = *(const f32x2*)(out1 + (size_t)a1 * DDIM + e);
  const f32x2 x2 = *(const f32x2*)(out2 + (size_t)a2 * DDIM + e);

  float ap = fabsf(x1.x - x2.x) + fabsf(x1.y - x2.y);
#pragma unroll
  for (int o = 32; o > 0; o >>= 1) ap += __shfl_xor(ap, o, 64);
  const float Dm = ap + 1.0f;  // GAMMA = 1

  float s = 0.f;
  for (int k = 0; k < KK; k++) {
    const int n1 = neg[(size_t)t * KK + k];
    const int n2 = neg[(size_t)(TT + t) * KK + k];
    const f32x2 v1 = *(const f32x2*)(out2 + (size_t)n1 * DDIM + e);
    const f32x2 v2 = *(const f32x2*)(out1 + (size_t)n2 * DDIM + e);
    float d1 = fabsf(x1.x - v1.x) + fabsf(x1.y - v1.y);
    float d2 = fabsf(x2.x - v2.x) + fabsf(x2.y - v2.y);
#pragma unroll
    for (int o = 32; o > 0; o >>= 1) {
      d1 += __shfl_xor(d1, o, 64);
      d2 += __shfl_xor(d2, o, 64);
    }
    s += fmaxf(Dm - d1, 0.f) + fmaxf(Dm - d2, 0.f);
  }
  if (lane == 0) atomicAdd(out, s * (1.0f / (TT * KK)));
}

extern "C" void kernel_launch(void* const* d_in, const int* in_sizes, int n_in,
                              void* d_out, int out_size, void* d_ws,
                              size_t ws_size, hipStream_t stream) {
  const float* out1 = (const float*)d_in[0];
  const float* out2 = (const float*)d_in[1];
  const int* anc1 = (const int*)d_in[2];
  const int* anc2 = (const int*)d_in[3];

  // workspace: cand_val (5.24MB) | cand_idx (5.24MB) | neg (80KB)
  float* cand_val = (float*)d_ws;
  int* cand_idx = (int*)(cand_val + (size_t)NCH * 4 * KK * TT2);
  int* neg = cand_idx + (size_t)NCH * 4 * KK * TT2;
  float* out = (float*)d_out;

  hipLaunchKernelGGL(mine_kernel, dim3(2 * 16 * NCH), dim3(256), 0, stream,
                     out1, out2, anc1, anc2, cand_val, cand_idx);
  hipLaunchKernelGGL(merge1_kernel, dim3(64), dim3(256), 0, stream, cand_val,
                     cand_idx);
  hipLaunchKernelGGL(merge2_kernel, dim3(8), dim3(256), 0, stream, cand_val,
                     cand_idx, neg);
  hipLaunchKernelGGL(zero_kernel, dim3(1), dim3(64), 0, stream, out);
  hipLaunchKernelGGL(loss_kernel, dim3(TT / 4), dim3(256), 0, stream, out1,
                     out2, anc1, anc2, neg, out);
}

// Round 10
// 1213.955 us; speedup vs baseline: 17.6166x; 17.6166x over previous
//
#include <hip/hip_runtime.h>
#include <stdint.h>

// RankingLossL1: negative mining (L1 top-K) + margin ranking loss.
// N=50000 rows, D=128, T=1024 anchors/direction, K=10, GAMMA=1.
//
// Round-10. Post-mortems r4..r9: the only structure with NO pathological HBM
// traffic was r5's (1-wave blocks, global_load_lds staging, small body);
// its cost was the 128-reg anchor array being rematerialized from cache
// (~3x VALU). Big LDS-tiled bodies (r8/r9) spill catastrophically no matter
// how state is expressed. So: r5 structure + 4-lanes-per-anchor so the
// per-lane anchor fragment is f32x4 av[8] = 32 VGPRs (the size r4 proved
// register-resident).
//   * wave = 16 anchors x 4 quarter-lanes. Partial L1 over 32 dims, then
//     2x __shfl_xor (quad) -> full distance in all 4 lanes (identical),
//     redundant register top-10 per lane, lanes with q==0 write.
//   * G streams through double-buffered 8-row LDS tiles via
//     global_load_lds with PRE-SWIZZLED per-lane source (linear LDS dest):
//     row stored as 8x16B blocks j, block j = dims [q*32+j*4) for q=0..3.
//     Reader lane (g,q): ds_read_b128 at row*512 + q*16 + j*64 -> the 4
//     distinct addresses per request hit disjoint bank groups (no conflict),
//     16-way broadcast across anchor groups.
//   * 4096 one-wave blocks = 2 dirs x 64 tslots x 32 chunks; bid%8 == chunk%8
//     keeps per-XCD G working set small. 8KB LDS/block -> 16 blocks/CU.
//   * Two-stage merge (32 chunks -> 4 -> 1), then wave-per-t loss kernel.
//
// Top-k ties: only distance VALUES enter the loss sum, so boundary-tie index
// choices cannot change the scalar result beyond fp rounding.

#define NROWS 50000
#define DDIM  128
#define TT    1024
#define KK    10
#define NCH   32
#define CH    1563        // ceil(NROWS/32); last chunk = 1547 rows
#define TT2   (2 * TT)
#define TROWS 8           // G rows per LDS tile (4KB; x2 buffers = 8KB)

typedef float f32x2 __attribute__((ext_vector_type(2)));
typedef float f32x4 __attribute__((ext_vector_type(4)));

__device__ __forceinline__ void topk_insert(float (&val)[KK], int (&idx)[KK],
                                            float cv, int ci) {
  // fully unrolled sorted insert (ascending); static indices -> stays in VGPRs
#pragma unroll
  for (int i = 0; i < KK; i++) {
    const bool lt = cv < val[i];
    const float tv = lt ? val[i] : cv;
    const int ti = lt ? idx[i] : ci;
    val[i] = lt ? cv : val[i];
    idx[i] = lt ? ci : idx[i];
    cv = tv;
    ci = ti;
  }
}

// grid: 4096 blocks x 64 threads; bid = ((dir*64 + tslot) * 32) + chunk.
// bid%8 == chunk%8 -> same-XCD blocks share few chunks (L2 locality).
__global__ __launch_bounds__(64, 4) void mine_kernel(
    const float* __restrict__ out1, const float* __restrict__ out2,
    const int* __restrict__ anc1, const int* __restrict__ anc2,
    float* __restrict__ cand_val, int* __restrict__ cand_idx) {
  const int lane = threadIdx.x;
  const int bid = blockIdx.x;
  const int chunk = bid & 31;
  const int rest = bid >> 5;
  const int dir = rest >> 6;
  const int tslot = rest & 63;

  const float* __restrict__ A = dir ? out2 : out1;
  const float* __restrict__ G = dir ? out1 : out2;
  const int* __restrict__ anc = dir ? anc2 : anc1;

  const int g = lane >> 2;  // anchor-in-wave 0..15
  const int q = lane & 3;   // 32-dim quarter
  const int a = tslot * 16 + g;
  const int arow = anc[a];

  // 32-dim quarter of the anchor -> 8 f32x4 = 32 VGPRs (r4-proven promotable)
  f32x4 av[8];
  {
    const f32x4* ap = (const f32x4*)(A + (size_t)arow * DDIM + q * 32);
#pragma unroll
    for (int j = 0; j < 8; j++) av[j] = ap[j];
  }

  float val[KK];
  int idx[KK];
#pragma unroll
  for (int i = 0; i < KK; i++) {
    val[i] = 3.4e38f;
    idx[i] = 0;
  }

  const int r0 = chunk * CH;
  const int r1 = (r0 + CH < NROWS) ? (r0 + CH) : NROWS;
  const int nt = (r1 - r0 + TROWS - 1) / TROWS;

  // double-buffered swizzled G tile; one wave per block -> no barriers
  __shared__ float gt[2][TROWS * DDIM];

  // staging source permutation (lane-constant): LDS word W = c*256 + lane*4
  // -> row = c*2 + (lane>>5), within-row pos p = (lane&31)*4
  // -> j = (lane&31)>>2, q' = (lane&31)&3, source dim = q'*32 + j*4.
  const int srow = lane >> 5;
  const int sdim = ((lane & 31) & 3) * 32 + ((lane & 31) >> 2) * 4;

  auto STAGE = [&](int b, int rs) {
#pragma unroll
    for (int c = 0; c < 4; c++) {
      const float* src = G + (size_t)(rs + c * 2 + srow) * DDIM + sdim;
      float* dst = &gt[b][c * 256];  // wave-uniform base; HW adds lane*16
      __builtin_amdgcn_global_load_lds(
          (const __attribute__((address_space(1))) uint32_t*)src,
          (__attribute__((address_space(3))) uint32_t*)dst, 16, 0, 0);
    }
  };
  auto RS = [&](int ts) { return ts > NROWS - TROWS ? NROWS - TROWS : ts; };

  STAGE(0, RS(r0));
  asm volatile("s_waitcnt vmcnt(0)" ::: "memory");

  int bufv = 0;
  for (int t = 0; t < nt; t++) {
    const int ts = r0 + t * TROWS;
    const int rs = RS(ts);
    if (t + 1 < nt) STAGE(bufv ^ 1, RS(ts + TROWS));  // overlap with compute

    const float* gb = &gt[bufv][0];
#pragma unroll
    for (int rr = 0; rr < TROWS; rr++) {
      const int r = ts + rr;
      if (r < r1) {  // wave-uniform
        // lane reads its quarter: bytes row*512 + q*16 + j*64 -> the 4
        // distinct addresses (q=0..3) hit disjoint bank groups.
        const f32x4* lp = (const f32x4*)&gb[(r - rs) * DDIM + q * 4];
        float c0 = 0.f, c1 = 0.f, c2 = 0.f, c3 = 0.f;
#pragma unroll
        for (int j = 0; j < 8; j++) {
          const f32x4 gv = lp[j * 4];  // +j*16 words = +64B
          const f32x4 d = av[j] - gv;
          c0 += fabsf(d.x);
          c1 += fabsf(d.y);
          c2 += fabsf(d.z);
          c3 += fabsf(d.w);
        }
        float p = (c0 + c1) + (c2 + c3);
        p += __shfl_xor(p, 1, 64);  // quad reduce: all 4 lanes get the
        p += __shfl_xor(p, 2, 64);  // bit-identical full distance
        if (p < val[KK - 1]) topk_insert(val, idx, p, r);
      }
    }
    asm volatile("s_waitcnt vmcnt(0)" ::: "memory");  // next tile landed
    bufv ^= 1;
  }

  // q==0 lane of each anchor writes its top-K
  // layout [chunk*KK + i][slot]: 16 consecutive slots -> coalesced-ish
  if (q == 0) {
    const int slot = dir * TT + a;
#pragma unroll
    for (int i = 0; i < KK; i++) {
      const size_t o = (size_t)(chunk * KK + i) * TT2 + slot;
      cand_val[o] = val[i];
      cand_idx[o] = idx[i];
    }
  }
}

// stage 1: 32 chunk-lists -> 4 per slot (8192 threads), in place
__global__ void merge1_kernel(float* __restrict__ cand_val,
                              int* __restrict__ cand_idx) {
  const int tid = blockIdx.x * blockDim.x + threadIdx.x;
  const int slot = tid & (TT2 - 1);
  const int part = tid >> 11;  // 0..3 (8 chunks each)
  float val[KK];
  int idx[KK];
#pragma unroll
  for (int i = 0; i < KK; i++) {
    val[i] = 3.4e38f;
    idx[i] = 0;
  }
  for (int c = 0; c < 8 * KK; c++) {  // rows part*80 .. part*80+79, coalesced
    const size_t o = (size_t)(part * 8 * KK + c) * TT2 + slot;
    const float v = cand_val[o];
    if (v < val[KK - 1]) topk_insert(val, idx, v, cand_idx[o]);
  }
#pragma unroll
  for (int i = 0; i < KK; i++) {
    const size_t o = (size_t)(part * 8 * KK + i) * TT2 + slot;
    cand_val[o] = val[i];
    cand_idx[o] = idx[i];
  }
}

// stage 2: 4 lists -> final negatives (2048 threads)
__global__ void merge2_kernel(const float* __restrict__ cand_val,
                              const int* __restrict__ cand_idx,
                              int* __restrict__ neg) {
  const int slot = blockIdx.x * blockDim.x + threadIdx.x;
  if (slot >= TT2) return;
  float val[KK];
  int idx[KK];
#pragma unroll
  for (int i = 0; i < KK; i++) {
    val[i] = 3.4e38f;
    idx[i] = 0;
  }
  for (int p = 0; p < 4; p++)
    for (int i = 0; i < KK; i++) {
      const size_t o = (size_t)(p * 8 * KK + i) * TT2 + slot;
      const float v = cand_val[o];
      if (v < val[KK - 1]) topk_insert(val, idx, v, cand_idx[o]);
    }
#pragma unroll
  for (int i = 0; i < KK; i++) neg[(size_t)slot * KK + i] = idx[i];
}

__global__ void zero_kernel(float* __restrict__ out) {
  if (threadIdx.x == 0) out[0] = 0.f;
}

__global__ void loss_kernel(const float* __restrict__ out1,
                            const float* __restrict__ out2,
                            const int* __restrict__ anc1,
                            const int* __restrict__ anc2,
                            const int* __restrict__ neg,  // [2][TT][KK]
                            float* __restrict__ out) {
  const int lane = threadIdx.x & 63;
  const int w = threadIdx.x >> 6;
  const int t = blockIdx.x * 4 + w;  // one wave per t
  const int a1 = anc1[t];
  const int a2 = anc2[t];
  const int e = lane * 2;

  const f32x2 x1 = *(const f32x2*)(out1 + (size_t)a1 * DDIM + e);
  const f32x2 x2 = *(const f32x2*)(out2 + (size_t)a2 * DDIM + e);

  float ap = fabsf(x1.x - x2.x) + fabsf(x1.y - x2.y);
#pragma unroll
  for (int o = 32; o > 0; o >>= 1) ap += __shfl_xor(ap, o, 64);
  const float Dm = ap + 1.0f;  // GAMMA = 1

  float s = 0.f;
  for (int k = 0; k < KK; k++) {
    const int n1 = neg[(size_t)t * KK + k];
    const int n2 = neg[(size_t)(TT + t) * KK + k];
    const f32x2 v1 = *(const f32x2*)(out2 + (size_t)n1 * DDIM + e);
    const f32x2 v2 = *(const f32x2*)(out1 + (size_t)n2 * DDIM + e);
    float d1 = fabsf(x1.x - v1.x) + fabsf(x1.y - v1.y);
    float d2 = fabsf(x2.x - v2.x) + fabsf(x2.y - v2.y);
#pragma unroll
    for (int o = 32; o > 0; o >>= 1) {
      d1 += __shfl_xor(d1, o, 64);
      d2 += __shfl_xor(d2, o, 64);
    }
    s += fmaxf(Dm - d1, 0.f) + fmaxf(Dm - d2, 0.f);
  }
  if (lane == 0) atomicAdd(out, s * (1.0f / (TT * KK)));
}

extern "C" void kernel_launch(void* const* d_in, const int* in_sizes, int n_in,
                              void* d_out, int out_size, void* d_ws,
                              size_t ws_size, hipStream_t stream) {
  const float* out1 = (const float*)d_in[0];
  const float* out2 = (const float*)d_in[1];
  const int* anc1 = (const int*)d_in[2];
  const int* anc2 = (const int*)d_in[3];

  // workspace: cand_val (2.62MB) | cand_idx (2.62MB) | neg (80KB)
  float* cand_val = (float*)d_ws;
  int* cand_idx = (int*)(cand_val + (size_t)NCH * KK * TT2);
  int* neg = cand_idx + (size_t)NCH * KK * TT2;
  float* out = (float*)d_out;

  hipLaunchKernelGGL(mine_kernel, dim3(2 * 64 * NCH), dim3(64), 0, stream,
                     out1, out2, anc1, anc2, cand_val, cand_idx);
  hipLaunchKernelGGL(merge1_kernel, dim3(32), dim3(256), 0, stream, cand_val,
                     cand_idx);
  hipLaunchKernelGGL(merge2_kernel, dim3(8), dim3(256), 0, stream, cand_val,
                     cand_idx, neg);
  hipLaunchKernelGGL(zero_kernel, dim3(1), dim3(64), 0, stream, out);
  hipLaunchKernelGGL(loss_kernel, dim3(TT / 4), dim3(256), 0, stream, out1,
                     out2, anc1, anc2, neg, out);
}